// Round 4
// baseline (83.696 us; speedup 1.0000x reference)
//
#include <hip/hip_runtime.h>
#include <math.h>

#define BB 8
#define HH 256
#define WW 256
#define NPIX (BB*HH*WW)   // 524288
#define BIGI 512          // H + W, the reference cap
#define BIGBIG (1<<20)
#define MAGIC 0x9E3779B97F4A7C15ull

// ws layout: 512 slots x 4 floats (16 B): {partial, pad, flag_lo, flag_hi}.
// No init needed: harness re-poisons ws each iteration (a repeated-dword fill
// can never equal the 64-bit MAGIC, whose halves differ), and flags are
// written fresh by each block with release/agent semantics.

#define ENV_GROUP(kk) { float4 v = s4[kk];                        \
    float D0 = fw - (float)(4 * (kk));                            \
    d2 = fminf(d2, fmaf(D0, D0, v.x));                            \
    float D1 = D0 - 1.0f; d2 = fminf(d2, fmaf(D1, D1, v.y));      \
    float D2 = D0 - 2.0f; d2 = fminf(d2, fmaf(D2, D2, v.z));      \
    float D3 = D0 - 3.0f; d2 = fminf(d2, fmaf(D3, D3, v.w)); }

// ---------------------------------------------------------------------------
// Single fused kernel. Grid 512 x 1024. Block (im = bid>>6, rg = bid&63)
// owns rows 4rg..4rg+3 of image im.
//  1) PACK: block rebuilds the full image's column bitmasks in LDS.
//     Wave v: column group cg=v&3 (lane=column -> coalesced 256B row loads),
//     row chunk rc=v>>2 (64 rows). __ballot per row is wave-uniform; lane l
//     extracts bit l -> builds 2 words/lane. 8KB LDS, no transpose, no k1.
//  2) Vertical distances per pixel via clz/ctz + cross-word carry chains
//     (identical arithmetic to the round-2/3 verified kernels).
//  3) Horizontal center-out lower envelope + loss (unchanged, verified).
//  4) Reduction without pre-zeroed ws: plain-store partial + MAGIC flag
//     (release/agent); block 0 polls all 512 flags (acquire/agent) and
//     writes out[0]. Waiters never block finishers -> deadlock-free.
// ---------------------------------------------------------------------------
__global__ __launch_bounds__(1024) void fused_boundary_all(
    const float* __restrict__ pred,
    const float* __restrict__ tgt,
    float* __restrict__ ws,
    float* __restrict__ out) {
  __shared__ unsigned int Mlds[8][WW];          // 8 KB column bitmasks
  __shared__ __align__(16) float lA[4][WW];
  __shared__ __align__(16) float lB[4][WW];
  __shared__ float wsum[16];

  int tid = threadIdx.x;
  int bid = blockIdx.x;
  int im = bid >> 6;
  int rg = bid & 63;

  // ---- 1) pack whole image into LDS bitmasks ----
  {
    int wv = tid >> 6, lane = tid & 63;
    int cg = wv & 3, rc = wv >> 2;
    int col = (cg << 6) + lane;
    size_t ib = (size_t)im * (HH * WW) + col;
    unsigned int m0 = 0, m1 = 0;
#pragma unroll
    for (int i = 0; i < 32; ++i) {
      float t = tgt[ib + (size_t)((rc << 6) + i) * WW];
      unsigned long long bal = __ballot(t > 0.5f);
      m0 |= ((unsigned int)(bal >> lane) & 1u) << i;
    }
#pragma unroll
    for (int i = 0; i < 32; ++i) {
      float t = tgt[ib + (size_t)((rc << 6) + 32 + i) * WW];
      unsigned long long bal = __ballot(t > 0.5f);
      m1 |= ((unsigned int)(bal >> lane) & 1u) << i;
    }
    Mlds[2 * rc][col] = m0;
    Mlds[2 * rc + 1][col] = m1;
  }

  float x = pred[(size_t)bid * 1024 + tid];   // coalesced, overlaps pack
  __syncthreads();

  int r = tid >> 8;           // row within group (wave-uniform)
  int w = tid & 255;          // column
  int R = 4 * rg + r;         // row in image
  int k = R >> 5;             // word id (wave-uniform)
  int rr = R & 31;            // bit within word

  unsigned int M[8];
#pragma unroll
  for (int j = 0; j < 8; ++j) M[j] = Mlds[j][w];

  // ---- 2) cross-word carries (A = bg = ~fg, B = fg) — verified chains ----
  int fcA = BIGBIG, fcB = BIGBIG, bcA = BIGBIG, bcB = BIGBIG;
  {
    int cA = BIGBIG, cB = BIGBIG;
#pragma unroll
    for (int j = 0; j < 8; ++j) {
      if (j == k) { fcA = cA; fcB = cB; }
      unsigned int a = ~M[j], bm = M[j];
      cA = a  ? (int)__builtin_clz(a)  : cA + 32;
      cB = bm ? (int)__builtin_clz(bm) : cB + 32;
    }
  }
  {
    int cA = BIGBIG, cB = BIGBIG;
#pragma unroll
    for (int j = 7; j >= 0; --j) {
      if (j == k) { bcA = cA; bcB = cB; }
      unsigned int a = ~M[j], bm = M[j];
      cA = a  ? (int)__builtin_ctz(a)  : cA + 32;
      cB = bm ? (int)__builtin_ctz(bm) : cB + 32;
    }
  }

  unsigned int mk = M[k];
  bool fg = (mk >> rr) & 1u;
  float t = fg ? 1.0f : 0.0f;

  {
    unsigned int mA = ~mk;
    unsigned int xx = mA << (31 - rr);
    unsigned int yy = mA >> rr;
    int df = xx ? (int)__builtin_clz(xx) : (rr + 1 + fcA);
    int db = yy ? (int)__builtin_ctz(yy) : (32 - rr + bcA);
    int d = min(min(df, db), BIGI);
    lA[r][w] = (float)(d * d);
  }
  {
    unsigned int xx = mk << (31 - rr);
    unsigned int yy = mk >> rr;
    int df = xx ? (int)__builtin_clz(xx) : (rr + 1 + fcB);
    int db = yy ? (int)__builtin_ctz(yy) : (32 - rr + bcB);
    int d = min(min(df, db), BIGI);
    lB[r][w] = (float)(d * d);
  }
  __syncthreads();

  // ---- 3) center-out lower envelope + loss (unchanged) ----
  const float4* s4 = (const float4*)(fg ? lA[r] : lB[r]);

  int w0 = w & ~63;
  int kc0 = w0 >> 2;
  float fw = (float)w;
  float d2 = 1e30f;

#pragma unroll 4
  for (int kk = kc0; kk < kc0 + 16; ++kk) ENV_GROUP(kk);

  int kL = kc0 - 1;
  int kR = kc0 + 16;
  for (int iter = 0; iter < 16; ++iter) {
    int bL = (kL >= 0) ? (w0 - 4 * kL - 3) : 100000;
    int bR = (kR <= 63) ? (4 * kR - w0 - 63) : 100000;
    int bb = min(bL, bR);
    float bb2 = (float)bb * (float)bb;
    if (__all(d2 <= bb2)) break;
    if (kL >= 0) { ENV_GROUP(kL); kL--; }
    if (kR <= 63) { ENV_GROUP(kR); kR++; }
  }

  float dd = sqrtf(d2);
  float weight = 1.0f / (1.0f + __expf((dd - 3.0f) * 0.2f));
  float bce = fmaxf(x, 0.0f) - x * t + log1pf(__expf(-fabsf(x)));
  float c = bce * weight * (1.0f / (float)NPIX);

  // ---- 4) block reduce -> slot store + flag ----
#pragma unroll
  for (int off = 32; off > 0; off >>= 1) c += __shfl_down(c, off, 64);
  if ((tid & 63) == 0) wsum[tid >> 6] = c;
  __syncthreads();

  if (tid < 64) {
    float v = (tid < 16) ? wsum[tid] : 0.0f;
#pragma unroll
    for (int off = 8; off > 0; off >>= 1) v += __shfl_down(v, off, 64);
    if (tid == 0) {
      float* slot = ws + (size_t)bid * 4;
      slot[0] = v;
      __threadfence();
      __hip_atomic_store((unsigned long long*)(slot + 2), MAGIC,
                         __ATOMIC_RELEASE, __HIP_MEMORY_SCOPE_AGENT);
    }
  }

  // ---- block 0: poll all 512 flags, final reduce, write out ----
  if (bid == 0) {
    __syncthreads();
    float v = 0.0f;
    if (tid < 512) {
      unsigned long long* fp = (unsigned long long*)(ws + (size_t)tid * 4 + 2);
      while (__hip_atomic_load(fp, __ATOMIC_ACQUIRE,
                               __HIP_MEMORY_SCOPE_AGENT) != MAGIC)
        __builtin_amdgcn_s_sleep(8);
      v = ws[(size_t)tid * 4];
    }
#pragma unroll
    for (int off = 32; off > 0; off >>= 1) v += __shfl_down(v, off, 64);
    if ((tid & 63) == 0) wsum[tid >> 6] = v;
    __syncthreads();
    if (tid < 64) {
      float s = (tid < 16) ? wsum[tid] : 0.0f;
#pragma unroll
      for (int off = 8; off > 0; off >>= 1) s += __shfl_down(s, off, 64);
      if (tid == 0) out[0] = s;
    }
  }
}

extern "C" void kernel_launch(void* const* d_in, const int* in_sizes, int n_in,
                              void* d_out, int out_size, void* d_ws, size_t ws_size,
                              hipStream_t stream) {
  const float* pred = (const float*)d_in[0];
  const float* tgt  = (const float*)d_in[1];
  float* out = (float*)d_out;
  float* ws  = (float*)d_ws;

  fused_boundary_all<<<dim3(512), dim3(1024), 0, stream>>>(pred, tgt, ws, out);
}